// Round 9
// baseline (135.614 us; speedup 1.0000x reference)
//
#include <hip/hip_runtime.h>
#include <hip/hip_bf16.h>

// ---------------- types ----------------
typedef float f32x4 __attribute__((ext_vector_type(4)));
typedef float f32x16 __attribute__((ext_vector_type(16)));
typedef __bf16 v8bf __attribute__((ext_vector_type(8)));
typedef unsigned short ushortx4 __attribute__((ext_vector_type(4)));
typedef unsigned short ushortx8 __attribute__((ext_vector_type(8)));
typedef unsigned int uint4v __attribute__((ext_vector_type(4)));

#define NIMG 16
#define CCH  256
#define HWP  1600
#define APIT 264   // A-tile pitch (bf16 elems): 528B = 33*16, 16B aligned

__device__ __forceinline__ unsigned short f2bf(float f) {
  unsigned int u = __builtin_bit_cast(unsigned int, f);
  u = (u + 0x7FFFu + ((u >> 16) & 1u)) >> 16;
  return (unsigned short)u;
}

__device__ __forceinline__ f32x4 mfma16(v8bf a, v8bf b, f32x4 c) {
  return __builtin_amdgcn_mfma_f32_16x16x32_bf16(a, b, c, 0, 0, 0);
}

__device__ __forceinline__ unsigned cvtpk(float a, float b) {
  unsigned r;
  asm("v_cvt_pk_bf16_f32 %0, %1, %2" : "=v"(r) : "v"(a), "v"(b));
  return r;
}
#define PSWAP(a, b) asm("v_permlane32_swap_b32 %0, %1" : "+v"(a), "+v"(b))

// ---------------- kernel A: weight->bf16 frag repack + PE table ----------------
__global__ void prep_kernel(const float* __restrict__ qkv_w,
                            float* __restrict__ pe,
                            unsigned short* __restrict__ w_frag) {
  int tid = blockIdx.x * blockDim.x + threadIdx.x;
  int nthr = gridDim.x * blockDim.x;
  for (int i = tid; i < 768 * 256; i += nthr) {
    int o = i >> 8, c = i & 255;
    int tile = o >> 4, lr = o & 15;
    int ks = c >> 5, lg = (c >> 3) & 3, e = c & 7;
    w_frag[(((size_t)tile * 8 + ks) * 64 + lg * 16 + lr) * 8 + e] = f2bf(qkv_w[i]);
  }
  const float c1 = 9.210340371976184f / 64.f;  // ln(10000)/64
  for (int i = tid; i < HWP * 256; i += nthr) {
    int p = i >> 8, c = i & 255;
    int j = p % 40, ii = p / 40;             // x = j (col), y = ii (row)
    int tt = c & 63;
    float omega = expf(-(float)tt * c1);
    float coord = (c < 128) ? (float)j : (float)ii;
    float a = coord * omega;
    pe[i] = ((c & 64) == 0) ? sinf(a) : cosf(a);
  }
}

// ---------------- kernel B: LN + QKV GEMM + PE, direct frag-layout stores ----------------
__global__ __launch_bounds__(512, 4) void ln_qkv_kernel(
    const float* __restrict__ x, const float* __restrict__ ln_w, const float* __restrict__ ln_b,
    const unsigned short* __restrict__ w_frag, const float* __restrict__ qkv_b,
    const float* __restrict__ pe,
    unsigned short* __restrict__ q_arr, unsigned short* __restrict__ k_arr,
    unsigned short* __restrict__ v_arr) {
  __shared__ unsigned short buf[64][APIT];     // 33.8 KB A-tile
  __shared__ float red_s[8][64], red_q[8][64];
  __shared__ float mu_s[64], rs_s[64];

  int t = threadIdx.x;
  int n = blockIdx.x / 25, pt = blockIdx.x % 25;
  int pix0 = pt * 64;
  int p = t & 63, g = t >> 6;
  const float* xb = x + (size_t)n * CCH * HWP + pix0;

  // pass 1: LN stats (x re-read in pass 2 from L2)
  {
    float sum = 0.f, sq = 0.f;
#pragma unroll
    for (int i = 0; i < 32; ++i) {
      float v = xb[(size_t)(g * 32 + i) * HWP + p];
      sum += v; sq += v * v;
    }
    red_s[g][p] = sum; red_q[g][p] = sq;
  }
  __syncthreads();
  if (t < 64) {
    float s = 0.f, q2 = 0.f;
#pragma unroll
    for (int gg = 0; gg < 8; ++gg) { s += red_s[gg][t]; q2 += red_q[gg][t]; }
    float mu = s * (1.f / 256.f);
    float var = q2 * (1.f / 256.f) - mu * mu;
    mu_s[t] = mu;
    rs_s[t] = rsqrtf(var + 1e-5f);
  }
  __syncthreads();
  {
    float mu = mu_s[p], rs = rs_s[p];
#pragma unroll
    for (int i4 = 0; i4 < 8; ++i4) {
      int c0 = g * 32 + i4 * 4;
      f32x4 lw = *(const f32x4*)&ln_w[c0];
      f32x4 lb = *(const f32x4*)&ln_b[c0];
      ushortx4 pk;
#pragma unroll
      for (int r = 0; r < 4; ++r) {
        float v = xb[(size_t)(c0 + r) * HWP + p];
        pk[r] = f2bf((v - mu) * rs * lw[r] + lb[r]);
      }
      *(ushortx4*)&buf[p][c0] = pk;
    }
  }
  __syncthreads();

  // GEMM: A = weights (frag-arranged global), B = x-tile (LDS)
  int w = t >> 6, l = t & 63, lr = l & 15, lg = l >> 4;
  f32x4 acc[6][4];
#pragma unroll
  for (int nf = 0; nf < 6; ++nf)
#pragma unroll
    for (int mi = 0; mi < 4; ++mi) acc[nf][mi] = (f32x4){0.f, 0.f, 0.f, 0.f};

#pragma unroll
  for (int ks = 0; ks < 8; ++ks) {
    v8bf bF[4];
#pragma unroll
    for (int mi = 0; mi < 4; ++mi)
      bF[mi] = *(const v8bf*)&buf[mi * 16 + lr][ks * 32 + lg * 8];
#pragma unroll
    for (int nf = 0; nf < 6; ++nf) {
      int tile = w + nf * 8;
      v8bf wf = *(const v8bf*)&w_frag[(((size_t)tile * 8 + ks) * 64 + l) * 8];
#pragma unroll
      for (int mi = 0; mi < 4; ++mi) acc[nf][mi] = mfma16(wf, bF[mi], acc[nf][mi]);
    }
  }

  // epilogue: acc[nf][mi][r] -> channel o = tile*16+lg*4+r, pixel pix0+mi*16+lr
  int lgh = lg >> 1, lgl = lg & 1;
  // ---- q (tiles 0..15): +bias +pe, *1/16, packed 8B stores ----
#pragma unroll
  for (int nf = 0; nf < 2; ++nf) {
    int tile = w + nf * 8;
    f32x4 bi = *(const f32x4*)&qkv_b[tile * 16 + lg * 4];
#pragma unroll
    for (int mi = 0; mi < 4; ++mi) {
      int pix = pix0 + mi * 16 + lr;
      f32x4 pev = *(const f32x4*)&pe[(size_t)pix * 256 + tile * 16 + lg * 4];
      f32x4 vv = (acc[nf][mi] + bi + pev) * 0.0625f;
      ushortx4 pk = {f2bf(vv[0]), f2bf(vv[1]), f2bf(vv[2]), f2bf(vv[3])};
      int qt = pix >> 5, l31 = pix & 31;
      size_t ad = ((((size_t)n * 50 + qt) * 16 + tile) * 2 + lgh) * 256 + l31 * 8 + lgl * 4;
      *(ushortx4*)&q_arr[ad] = pk;
    }
  }
  // ---- k (tiles 16..31): +bias +pe, packed 8B stores ----
#pragma unroll
  for (int nf = 2; nf < 4; ++nf) {
    int tile = w + nf * 8;
    int dt = tile - 16;
    f32x4 bi = *(const f32x4*)&qkv_b[tile * 16 + lg * 4];
#pragma unroll
    for (int mi = 0; mi < 4; ++mi) {
      int pix = pix0 + mi * 16 + lr;
      f32x4 pev = *(const f32x4*)&pe[(size_t)pix * 256 + dt * 16 + lg * 4];
      f32x4 vv = acc[nf][mi] + bi + pev;
      ushortx4 pk = {f2bf(vv[0]), f2bf(vv[1]), f2bf(vv[2]), f2bf(vv[3])};
      size_t ad = (((size_t)n * 16 + dt) * 1600 + pix) * 16 + lgh * 8 + lgl * 4;
      *(ushortx4*)&k_arr[ad] = pk;
    }
  }
  // ---- v (tiles 32..47): +bias, transposed scatter ----
#pragma unroll
  for (int nf = 4; nf < 6; ++nf) {
    int tile = w + nf * 8;
    f32x4 bi = *(const f32x4*)&qkv_b[tile * 16 + lg * 4];
#pragma unroll
    for (int mi = 0; mi < 4; ++mi) {
      int pix = pix0 + mi * 16 + lr;
      int kvs = pix >> 4, hi = (pix >> 3) & 1, e = pix & 7;
      f32x4 vv = acc[nf][mi] + bi;
      size_t vb = (((size_t)n * 100 + kvs) * 2 + hi) * 2048 + e;
      int d0 = (tile - 32) * 16 + lg * 4;
#pragma unroll
      for (int r = 0; r < 4; ++r)
        v_arr[vb + (size_t)(d0 + r) * 8] = f2bf(vv[r]);
    }
  }
}

// ---------------- kernel C: flash attention, 4 waves = 2 KV-halves x 2 D-halves ----------------
// 800 blocks (one 32-row q-tile each), all co-resident (~3.1 blocks/CU, VGPR ~100,
// LDS 32 KB) -> ~3.1 waves/SIMD for latency hiding. Per-wave body = proven round-7
// structure. In-block KV merge at the end: 2 barriers, all-literal acc indices.
__global__ __launch_bounds__(256, 2) void attn_kernel(
    const unsigned short* __restrict__ q_arr, const unsigned short* __restrict__ k_arr,
    const unsigned short* __restrict__ v_arr, const float* __restrict__ x,
    const float* __restrict__ gamma, float* __restrict__ out) {
  __shared__ float pool[8192];      // 32 KB: S-exchange (dbuf) / final KV-merge dump (reused)
  __shared__ float mls[4][2][32];   // [kvh*2+dh][{m,l}][q]

  int t = threadIdx.x;
  int wv = t >> 6, l = t & 63;
  int l31 = l & 31, hi = l >> 5;
  int kvh = wv & 1, dh = wv >> 1;
  int dto = dh * 8;      // 16-wide d-tile offset for q/k frags
  int dto32 = dh * 4;    // 32-wide d-tile offset for v/acc
  // XCD grouping: image n's 50 blocks land on XCD n%8 (K+V of 2 images fit one L2)
  int slot = blockIdx.x & 7, j = blockIdx.x >> 3;   // j in 0..99
  int n = slot + 8 * (j / 50);
  int qt = j % 50;
  int q0 = qt * 32;
  int kt0 = kvh * 25;    // this wave's KV half: tiles kt0..kt0+24

  // Q B-frags for this wave's d-half (pre-scaled by 1/16)
  v8bf qf[8];
  {
    const unsigned short* qp = q_arr + (((size_t)n * 50 + qt) * 32 + hi) * 256 + l31 * 8;
#pragma unroll
    for (int i = 0; i < 8; ++i)
      qf[i] = *(const v8bf*)(qp + (dto + i) * 512);
  }

  f32x16 acc[4];
#pragma unroll
  for (int dd = 0; dd < 4; ++dd)
#pragma unroll
    for (int r = 0; r < 16; ++r) acc[dd][r] = 0.f;

  float m_run = -1e30f, l_run = 0.f;

  const unsigned short* kbase = k_arr + (size_t)n * (16 * 1600 * 16) +
                                (size_t)dto * 25600 + hi * 8;
  const unsigned short* vbase = v_arr + (size_t)n * (100 * 2 * 256 * 8) +
                                hi * 2048 + l31 * 8 + dto32 * 256;

  // prologue: K frags (this wave's d-half) for first tile
  v8bf kc[8];
#pragma unroll
  for (int i = 0; i < 8; ++i)
    kc[i] = *(const v8bf*)(kbase + (size_t)i * 25600 + (kt0 * 32 + l31) * 16);

  for (int it = 0; it < 25; ++it) {
    int kt = kt0 + it;
    int pb = it & 1;
    int ktn = (it + 1 < 25) ? kt + 1 : kt0;

    // partial S^T[kv][q] over this wave's d-half (2 chains of 4)
    f32x16 s0, s1;
#pragma unroll
    for (int r = 0; r < 16; ++r) { s0[r] = 0.f; s1[r] = 0.f; }
#pragma unroll
    for (int i = 0; i < 8; i += 2) {
      s0 = __builtin_amdgcn_mfma_f32_32x32x16_bf16(kc[i], qf[i], s0, 0, 0, 0);
      s1 = __builtin_amdgcn_mfma_f32_32x32x16_bf16(kc[i + 1], qf[i + 1], s1, 0, 0, 0);
    }
    // kc dead -> reload same regs with next tile's K (long slack until next body)
#pragma unroll
    for (int i = 0; i < 8; ++i)
      kc[i] = *(const v8bf*)(kbase + (size_t)i * 25600 + (ktn * 32 + l31) * 16);

    // dump partial to LDS (conflict-free b128 pattern)
    int sxw = ((pb * 2 + kvh) * 2 + dh) * 1024;
#pragma unroll
    for (int r4 = 0; r4 < 4; ++r4) {
      f32x4 vv = {s0[r4 * 4 + 0] + s1[r4 * 4 + 0], s0[r4 * 4 + 1] + s1[r4 * 4 + 1],
                  s0[r4 * 4 + 2] + s1[r4 * 4 + 2], s0[r4 * 4 + 3] + s1[r4 * 4 + 3]};
      *(f32x4*)&pool[sxw + r4 * 256 + l * 4] = vv;
    }

    // V frags for THIS tile (consumed after softmax; latency hides under it)
    v8bf vf0[4], vf1[4];
    {
      const unsigned short* vp = vbase + (size_t)kt * 8192;
#pragma unroll
      for (int i = 0; i < 4; ++i) vf0[i] = *(const v8bf*)(vp + i * 256);
#pragma unroll
      for (int i = 0; i < 4; ++i) vf1[i] = *(const v8bf*)(vp + 4096 + i * 256);
    }

    __syncthreads();

    // full S (this kv-half) = own partial + partner d-half's partial
    int sxr = ((pb * 2 + kvh) * 2 + (dh ^ 1)) * 1024;
    float p[16];
#pragma unroll
    for (int r4 = 0; r4 < 4; ++r4) {
      f32x4 oth = *(const f32x4*)&pool[sxr + r4 * 256 + l * 4];
#pragma unroll
      for (int rr = 0; rr < 4; ++rr)
        p[r4 * 4 + rr] = (s0[r4 * 4 + rr] + s1[r4 * 4 + rr]) + oth[rr];
    }

    // online softmax: lane holds S rows kv=(r&3)+8*(r>>2)+4*hi for q=l31
    float t0 = fmaxf(p[0], p[1]), t1 = fmaxf(p[2], p[3]);
    float t2 = fmaxf(p[4], p[5]), t3 = fmaxf(p[6], p[7]);
    float t4 = fmaxf(p[8], p[9]), t5 = fmaxf(p[10], p[11]);
    float t6 = fmaxf(p[12], p[13]), t7 = fmaxf(p[14], p[15]);
    float mx = fmaxf(fmaxf(fmaxf(t0, t1), fmaxf(t2, t3)),
                     fmaxf(fmaxf(t4, t5), fmaxf(t6, t7)));
    mx = fmaxf(mx, __shfl_xor(mx, 32));
    if (!__all(mx <= m_run + 2.f)) {        // defer-rescale (e^2 headroom)
      float mnew = fmaxf(m_run, mx);
      float alpha = __expf(m_run - mnew);
      l_run *= alpha;
#pragma unroll
      for (int dd = 0; dd < 4; ++dd)
#pragma unroll
        for (int r = 0; r < 16; ++r) acc[dd][r] *= alpha;
      m_run = mnew;
    }
#pragma unroll
    for (int r = 0; r < 16; ++r) p[r] = __expf(p[r] - m_run);
    float sA = (p[0] + p[1]) + (p[2] + p[3]);
    float sB = (p[4] + p[5]) + (p[6] + p[7]);
    float sC = (p[8] + p[9]) + (p[10] + p[11]);
    float sD = (p[12] + p[13]) + (p[14] + p[15]);
    float sum = (sA + sB) + (sC + sD);
    sum += __shfl_xor(sum, 32);
    l_run += sum;

    // P -> bf16 B-frags via cvt_pk + permlane32_swap
    unsigned x0 = cvtpk(p[0], p[1]), x1 = cvtpk(p[2], p[3]);
    unsigned y0 = cvtpk(p[4], p[5]), y1 = cvtpk(p[6], p[7]);
    PSWAP(x0, y0); PSWAP(x1, y1);
    uint4v u0 = {x0, x1, y0, y1};
    v8bf pf0 = __builtin_bit_cast(v8bf, u0);
    unsigned z0 = cvtpk(p[8], p[9]), z1 = cvtpk(p[10], p[11]);
    unsigned w0 = cvtpk(p[12], p[13]), w1 = cvtpk(p[14], p[15]);
    PSWAP(z0, w0); PSWAP(z1, w1);
    uint4v u1 = {z0, z1, w0, w1};
    v8bf pf1 = __builtin_bit_cast(v8bf, u1);

    // O^T[d][q] += V^T · P^T  (this wave's 4 d-tiles only)
#pragma unroll
    for (int dd = 0; dd < 4; ++dd) {
      acc[dd] = __builtin_amdgcn_mfma_f32_32x32x16_bf16(vf0[dd], pf0, acc[dd], 0, 0, 0);
      acc[dd] = __builtin_amdgcn_mfma_f32_32x32x16_bf16(vf1[dd], pf1, acc[dd], 0, 0, 0);
    }
  }

  // ---------- in-block KV-half merge (2 barriers; pool reused; static indices) ----------
  __syncthreads();     // all waves past their last pool reads before we overwrite
  if (hi == 0) {
    mls[kvh * 2 + dh][0][l31] = m_run;
    mls[kvh * 2 + dh][1][l31] = l_run;
  }
  // each wave dumps the 2 d-tiles its partner will finalize
  if (kvh == 0) {
#pragma unroll
    for (int r4 = 0; r4 < 4; ++r4) {
      f32x4 a2 = {acc[2][r4 * 4 + 0], acc[2][r4 * 4 + 1], acc[2][r4 * 4 + 2], acc[2][r4 * 4 + 3]};
      f32x4 a3 = {acc[3][r4 * 4 + 0], acc[3][r4 * 4 + 1], acc[3][r4 * 4 + 2], acc[3][r4 * 4 + 3]};
      *(f32x4*)&pool[(((dh * 2 + 0) * 2 + 0) * 4 + r4) * 256 + l * 4] = a2;
      *(f32x4*)&pool[(((dh * 2 + 0) * 2 + 1) * 4 + r4) * 256 + l * 4] = a3;
    }
  } else {
#pragma unroll
    for (int r4 = 0; r4 < 4; ++r4) {
      f32x4 a0 = {acc[0][r4 * 4 + 0], acc[0][r4 * 4 + 1], acc[0][r4 * 4 + 2], acc[0][r4 * 4 + 3]};
      f32x4 a1 = {acc[1][r4 * 4 + 0], acc[1][r4 * 4 + 1], acc[1][r4 * 4 + 2], acc[1][r4 * 4 + 3]};
      *(f32x4*)&pool[(((dh * 2 + 1) * 2 + 0) * 4 + r4) * 256 + l * 4] = a0;
      *(f32x4*)&pool[(((dh * 2 + 1) * 2 + 1) * 4 + r4) * 256 + l * 4] = a1;
    }
  }
  __syncthreads();

  float m_o = mls[(kvh ^ 1) * 2 + dh][0][l31];
  float l_o = mls[(kvh ^ 1) * 2 + dh][1][l31];
  float M = fmaxf(m_run, m_o);
  float a_s = __expf(m_run - M), a_o = __expf(m_o - M);
  float linv = 1.f / (l_run * a_s + l_o * a_o);
  float gm = gamma[0];

#define FIN(DT, PK, S)                                                          \
  {                                                                             \
    _Pragma("unroll")                                                           \
    for (int r4 = 0; r4 < 4; ++r4) {                                            \
      f32x4 oth = *(const f32x4*)&pool[(((dh * 2 + (PK)) * 2 + (S)) * 4 + r4) * 256 + l * 4]; \
      _Pragma("unroll")                                                         \
      for (int rr = 0; rr < 4; ++rr) {                                          \
        int r = r4 * 4 + rr;                                                    \
        float o = acc[DT][r] * a_s + oth[rr] * a_o;                             \
        int d = (dto32 + (DT)) * 32 + (r & 3) + 8 * (r >> 2) + 4 * hi;          \
        size_t base = ((size_t)n * 256 + d) * HWP + q0 + l31;                   \
        out[base] = x[base] + gm * o * linv;                                    \
      }                                                                         \
    }                                                                           \
  }
  if (kvh == 0) { FIN(0, 1, 0); FIN(1, 1, 1); }   // partner kvh=1 dumped its acc[0],acc[1]
  else          { FIN(2, 0, 0); FIN(3, 0, 1); }   // partner kvh=0 dumped its acc[2],acc[3]
#undef FIN
}

// ---------------- launcher ----------------
extern "C" void kernel_launch(void* const* d_in, const int* in_sizes, int n_in,
                              void* d_out, int out_size, void* d_ws, size_t ws_size,
                              hipStream_t stream) {
  const float* x     = (const float*)d_in[0];
  const float* ln_w  = (const float*)d_in[1];
  const float* ln_b  = (const float*)d_in[2];
  const float* qkv_w = (const float*)d_in[3];
  const float* qkv_b = (const float*)d_in[4];
  const float* gamma = (const float*)d_in[5];
  float* out = (float*)d_out;

  char* ws = (char*)d_ws;
  unsigned short* w_frag = (unsigned short*)ws;              //   393,216 B
  float*          pe     = (float*)(ws + 393216);            // 1,638,400 B
  unsigned short* q_arr  = (unsigned short*)(ws + 2031616);    // 13,107,200 B
  unsigned short* k_arr  = (unsigned short*)(ws + 15138816);   // 13,107,200 B
  unsigned short* v_arr  = (unsigned short*)(ws + 28246016);   // 13,107,200 B

  hipLaunchKernelGGL(prep_kernel, dim3(384), dim3(256), 0, stream, qkv_w, pe, w_frag);
  hipLaunchKernelGGL(ln_qkv_kernel, dim3(400), dim3(512), 0, stream,
                     x, ln_w, ln_b, w_frag, qkv_b, pe, q_arr, k_arr, v_arr);
  hipLaunchKernelGGL(attn_kernel, dim3(800), dim3(256), 0, stream,
                     q_arr, k_arr, v_arr, x, gamma, out);
}

// Round 10
// 122.673 us; speedup vs baseline: 1.1055x; 1.1055x over previous
//
#include <hip/hip_runtime.h>
#include <hip/hip_bf16.h>

// ---------------- types ----------------
typedef float f32x4 __attribute__((ext_vector_type(4)));
typedef float f32x16 __attribute__((ext_vector_type(16)));
typedef __bf16 v8bf __attribute__((ext_vector_type(8)));
typedef unsigned short ushortx4 __attribute__((ext_vector_type(4)));
typedef unsigned short ushortx8 __attribute__((ext_vector_type(8)));
typedef unsigned int uint4v __attribute__((ext_vector_type(4)));

#define NIMG 16
#define CCH  256
#define HWP  1600
#define APIT 264   // A-tile pitch (bf16 elems): 528B = 33*16, 16B aligned

// q pre-scale: (1/sqrt(256)) * log2(e)  -> softmax runs in log2 domain (v_exp_f32 = 2^x)
#define QSCALE 0.09016844f
#define DEFER_THR 2.885390f   // 2.0 * log2(e)

__device__ __forceinline__ unsigned short f2bf(float f) {
  unsigned int u = __builtin_bit_cast(unsigned int, f);
  u = (u + 0x7FFFu + ((u >> 16) & 1u)) >> 16;
  return (unsigned short)u;
}

__device__ __forceinline__ f32x4 mfma16(v8bf a, v8bf b, f32x4 c) {
  return __builtin_amdgcn_mfma_f32_16x16x32_bf16(a, b, c, 0, 0, 0);
}

__device__ __forceinline__ unsigned cvtpk(float a, float b) {
  unsigned r;
  asm("v_cvt_pk_bf16_f32 %0, %1, %2" : "=v"(r) : "v"(a), "v"(b));
  return r;
}
__device__ __forceinline__ float exp2v(float x) {
  float r;
  asm("v_exp_f32 %0, %1" : "=v"(r) : "v"(x));
  return r;
}
#define PSWAP(a, b) asm("v_permlane32_swap_b32 %0, %1" : "+v"(a), "+v"(b))

// ---------------- kernel A: weight->bf16 frag repack + PE table ----------------
__global__ void prep_kernel(const float* __restrict__ qkv_w,
                            float* __restrict__ pe,
                            unsigned short* __restrict__ w_frag) {
  int tid = blockIdx.x * blockDim.x + threadIdx.x;
  int nthr = gridDim.x * blockDim.x;
  for (int i = tid; i < 768 * 256; i += nthr) {
    int o = i >> 8, c = i & 255;
    int tile = o >> 4, lr = o & 15;
    int ks = c >> 5, lg = (c >> 3) & 3, e = c & 7;
    w_frag[(((size_t)tile * 8 + ks) * 64 + lg * 16 + lr) * 8 + e] = f2bf(qkv_w[i]);
  }
  const float c1 = 9.210340371976184f / 64.f;  // ln(10000)/64
  for (int i = tid; i < HWP * 256; i += nthr) {
    int p = i >> 8, c = i & 255;
    int j = p % 40, ii = p / 40;             // x = j (col), y = ii (row)
    int tt = c & 63;
    float omega = expf(-(float)tt * c1);
    float coord = (c < 128) ? (float)j : (float)ii;
    float a = coord * omega;
    pe[i] = ((c & 64) == 0) ? sinf(a) : cosf(a);
  }
}

// ---------------- kernel B: LN + QKV GEMM + PE, direct frag-layout stores ----------------
__global__ __launch_bounds__(512, 4) void ln_qkv_kernel(
    const float* __restrict__ x, const float* __restrict__ ln_w, const float* __restrict__ ln_b,
    const unsigned short* __restrict__ w_frag, const float* __restrict__ qkv_b,
    const float* __restrict__ pe,
    unsigned short* __restrict__ q_arr, unsigned short* __restrict__ k_arr,
    unsigned short* __restrict__ v_arr) {
  __shared__ unsigned short buf[64][APIT];     // 33.8 KB A-tile
  __shared__ float red_s[8][64], red_q[8][64];
  __shared__ float mu_s[64], rs_s[64];

  int t = threadIdx.x;
  int n = blockIdx.x / 25, pt = blockIdx.x % 25;
  int pix0 = pt * 64;
  int p = t & 63, g = t >> 6;
  const float* xb = x + (size_t)n * CCH * HWP + pix0;

  // pass 1: LN stats (x re-read in pass 2 from L2)
  {
    float sum = 0.f, sq = 0.f;
#pragma unroll
    for (int i = 0; i < 32; ++i) {
      float v = xb[(size_t)(g * 32 + i) * HWP + p];
      sum += v; sq += v * v;
    }
    red_s[g][p] = sum; red_q[g][p] = sq;
  }
  __syncthreads();
  if (t < 64) {
    float s = 0.f, q2 = 0.f;
#pragma unroll
    for (int gg = 0; gg < 8; ++gg) { s += red_s[gg][t]; q2 += red_q[gg][t]; }
    float mu = s * (1.f / 256.f);
    float var = q2 * (1.f / 256.f) - mu * mu;
    mu_s[t] = mu;
    rs_s[t] = rsqrtf(var + 1e-5f);
  }
  __syncthreads();
  {
    float mu = mu_s[p], rs = rs_s[p];
#pragma unroll
    for (int i4 = 0; i4 < 8; ++i4) {
      int c0 = g * 32 + i4 * 4;
      f32x4 lw = *(const f32x4*)&ln_w[c0];
      f32x4 lb = *(const f32x4*)&ln_b[c0];
      ushortx4 pk;
#pragma unroll
      for (int r = 0; r < 4; ++r) {
        float v = xb[(size_t)(c0 + r) * HWP + p];
        pk[r] = f2bf((v - mu) * rs * lw[r] + lb[r]);
      }
      *(ushortx4*)&buf[p][c0] = pk;
    }
  }
  __syncthreads();

  // GEMM: A = weights (frag-arranged global), B = x-tile (LDS)
  int w = t >> 6, l = t & 63, lr = l & 15, lg = l >> 4;
  f32x4 acc[6][4];
#pragma unroll
  for (int nf = 0; nf < 6; ++nf)
#pragma unroll
    for (int mi = 0; mi < 4; ++mi) acc[nf][mi] = (f32x4){0.f, 0.f, 0.f, 0.f};

#pragma unroll
  for (int ks = 0; ks < 8; ++ks) {
    v8bf bF[4];
#pragma unroll
    for (int mi = 0; mi < 4; ++mi)
      bF[mi] = *(const v8bf*)&buf[mi * 16 + lr][ks * 32 + lg * 8];
#pragma unroll
    for (int nf = 0; nf < 6; ++nf) {
      int tile = w + nf * 8;
      v8bf wf = *(const v8bf*)&w_frag[(((size_t)tile * 8 + ks) * 64 + l) * 8];
#pragma unroll
      for (int mi = 0; mi < 4; ++mi) acc[nf][mi] = mfma16(wf, bF[mi], acc[nf][mi]);
    }
  }

  // epilogue: acc[nf][mi][r] -> channel o = tile*16+lg*4+r, pixel pix0+mi*16+lr
  int lgh = lg >> 1, lgl = lg & 1;
  // ---- q (tiles 0..15): +bias +pe, *QSCALE (log2-domain softmax), packed 8B stores ----
#pragma unroll
  for (int nf = 0; nf < 2; ++nf) {
    int tile = w + nf * 8;
    f32x4 bi = *(const f32x4*)&qkv_b[tile * 16 + lg * 4];
#pragma unroll
    for (int mi = 0; mi < 4; ++mi) {
      int pix = pix0 + mi * 16 + lr;
      f32x4 pev = *(const f32x4*)&pe[(size_t)pix * 256 + tile * 16 + lg * 4];
      f32x4 vv = (acc[nf][mi] + bi + pev) * QSCALE;
      ushortx4 pk = {f2bf(vv[0]), f2bf(vv[1]), f2bf(vv[2]), f2bf(vv[3])};
      int qt = pix >> 5, l31 = pix & 31;
      size_t ad = ((((size_t)n * 50 + qt) * 16 + tile) * 2 + lgh) * 256 + l31 * 8 + lgl * 4;
      *(ushortx4*)&q_arr[ad] = pk;
    }
  }
  // ---- k (tiles 16..31): +bias +pe, packed 8B stores ----
#pragma unroll
  for (int nf = 2; nf < 4; ++nf) {
    int tile = w + nf * 8;
    int dt = tile - 16;
    f32x4 bi = *(const f32x4*)&qkv_b[tile * 16 + lg * 4];
#pragma unroll
    for (int mi = 0; mi < 4; ++mi) {
      int pix = pix0 + mi * 16 + lr;
      f32x4 pev = *(const f32x4*)&pe[(size_t)pix * 256 + dt * 16 + lg * 4];
      f32x4 vv = acc[nf][mi] + bi + pev;
      ushortx4 pk = {f2bf(vv[0]), f2bf(vv[1]), f2bf(vv[2]), f2bf(vv[3])};
      size_t ad = (((size_t)n * 16 + dt) * 1600 + pix) * 16 + lgh * 8 + lgl * 4;
      *(ushortx4*)&k_arr[ad] = pk;
    }
  }
  // ---- v (tiles 32..47): +bias, transposed scatter ----
#pragma unroll
  for (int nf = 4; nf < 6; ++nf) {
    int tile = w + nf * 8;
    f32x4 bi = *(const f32x4*)&qkv_b[tile * 16 + lg * 4];
#pragma unroll
    for (int mi = 0; mi < 4; ++mi) {
      int pix = pix0 + mi * 16 + lr;
      int kvs = pix >> 4, hi = (pix >> 3) & 1, e = pix & 7;
      f32x4 vv = acc[nf][mi] + bi;
      size_t vb = (((size_t)n * 100 + kvs) * 2 + hi) * 2048 + e;
      int d0 = (tile - 32) * 16 + lg * 4;
#pragma unroll
      for (int r = 0; r < 4; ++r)
        v_arr[vb + (size_t)(d0 + r) * 8] = f2bf(vv[r]);
    }
  }
}

// ---------------- kernel C: flash attention, 2 waves/block, D-split, PIPELINED ----------------
// Iteration t: barrier -> read partner S(t) -> [softmax(t) VALU || QK(t+1) MFMA] ->
// PV(t) -> write S(t+1) -> prefetch K(t+2), V(t+1). 4-buffer LDS ring, 1 barrier/iter.
__global__ __launch_bounds__(128, 2) void attn_kernel(
    const unsigned short* __restrict__ q_arr, const unsigned short* __restrict__ k_arr,
    const unsigned short* __restrict__ v_arr, const float* __restrict__ x,
    const float* __restrict__ gamma, float* __restrict__ out) {
  __shared__ float sx[4][2][4][64][4];   // [buf][wave][r4][lane][4] = 32 KB

  int t = threadIdx.x;
  int wv = t >> 6, l = t & 63;
  int l31 = l & 31, hi = l >> 5;
  int dto = wv * 8;      // 16-wide d-tile offset for q/k frags
  int dto32 = wv * 4;    // 32-wide d-tile offset for v/acc
  // XCD grouping: image n's 50 blocks land on XCD n%8 (K+V of 2 images fit one L2)
  int slot = blockIdx.x & 7, j = blockIdx.x >> 3;   // j in 0..99
  int n = slot + 8 * (j / 50);
  int qt = j % 50;
  int q0 = qt * 32;

  // Q B-frags for this wave's d-half (pre-scaled by QSCALE)
  v8bf qf[8];
  {
    const unsigned short* qp = q_arr + (((size_t)n * 50 + qt) * 32 + hi) * 256 + l31 * 8;
#pragma unroll
    for (int i = 0; i < 8; ++i)
      qf[i] = *(const v8bf*)(qp + (dto + i) * 512);
  }

  f32x16 acc[4];
#pragma unroll
  for (int dd = 0; dd < 4; ++dd)
#pragma unroll
    for (int r = 0; r < 16; ++r) acc[dd][r] = 0.f;

  float m_run = -1e30f, l_run = 0.f;

  const unsigned short* kbase = k_arr + (size_t)n * (16 * 1600 * 16) +
                                (size_t)dto * 25600 + hi * 8;
  const unsigned short* vbase = v_arr + (size_t)n * (100 * 2 * 256 * 8) +
                                hi * 2048 + l31 * 8 + dto32 * 256;

  // ---- prologue: S(0) partial, write buf0; prefetch K(1), V(0) ----
  v8bf kc[8];
#pragma unroll
  for (int i = 0; i < 8; ++i)
    kc[i] = *(const v8bf*)(kbase + (size_t)i * 25600 + l31 * 16);

  f32x16 sA, sB;
#pragma unroll
  for (int r = 0; r < 16; ++r) sA[r] = 0.f;
#pragma unroll
  for (int i = 0; i < 8; ++i)
    sA = __builtin_amdgcn_mfma_f32_32x32x16_bf16(kc[i], qf[i], sA, 0, 0, 0);

#pragma unroll
  for (int r4 = 0; r4 < 4; ++r4) {
    f32x4 vv = {sA[r4 * 4 + 0], sA[r4 * 4 + 1], sA[r4 * 4 + 2], sA[r4 * 4 + 3]};
    *(f32x4*)&sx[0][wv][r4][l][0] = vv;
  }
#pragma unroll
  for (int i = 0; i < 8; ++i)
    kc[i] = *(const v8bf*)(kbase + (size_t)i * 25600 + (32 + l31) * 16);

  v8bf vf0[4], vf1[4];
#pragma unroll
  for (int i = 0; i < 4; ++i) vf0[i] = *(const v8bf*)(vbase + i * 256);
#pragma unroll
  for (int i = 0; i < 4; ++i) vf1[i] = *(const v8bf*)(vbase + 4096 + i * 256);

  // ---- pipelined body ----
  auto body = [&](int kt, f32x16& scur, f32x16& snxt, bool nexttile) {
    __syncthreads();
    int br = kt & 3;
    // partner partial read + combine
    float p[16];
#pragma unroll
    for (int r4 = 0; r4 < 4; ++r4) {
      f32x4 oth = *(const f32x4*)&sx[br][wv ^ 1][r4][l][0];
#pragma unroll
      for (int rr = 0; rr < 4; ++rr)
        p[r4 * 4 + rr] = scur[r4 * 4 + rr] + oth[rr];
    }
    // QK(t+1) first half (MFMA pipe; interleaves with the VALU below)
    if (nexttile) {
#pragma unroll
      for (int r = 0; r < 16; ++r) snxt[r] = 0.f;
#pragma unroll
      for (int i = 0; i < 4; ++i)
        snxt = __builtin_amdgcn_mfma_f32_32x32x16_bf16(kc[i], qf[i], snxt, 0, 0, 0);
    }
    // max tree
    float t0 = fmaxf(p[0], p[1]), t1 = fmaxf(p[2], p[3]);
    float t2 = fmaxf(p[4], p[5]), t3 = fmaxf(p[6], p[7]);
    float t4 = fmaxf(p[8], p[9]), t5 = fmaxf(p[10], p[11]);
    float t6 = fmaxf(p[12], p[13]), t7 = fmaxf(p[14], p[15]);
    float mx = fmaxf(fmaxf(fmaxf(t0, t1), fmaxf(t2, t3)),
                     fmaxf(fmaxf(t4, t5), fmaxf(t6, t7)));
    mx = fmaxf(mx, __shfl_xor(mx, 32));
    if (!__all(mx <= m_run + DEFER_THR)) {   // defer-rescale (2^2.885 = e^2 headroom)
      float mnew = fmaxf(m_run, mx);
      float alpha = exp2v(m_run - mnew);
      l_run *= alpha;
#pragma unroll
      for (int dd = 0; dd < 4; ++dd)
#pragma unroll
        for (int r = 0; r < 16; ++r) acc[dd][r] *= alpha;
      m_run = mnew;
    }
    // QK(t+1) second half
    if (nexttile) {
#pragma unroll
      for (int i = 4; i < 8; ++i)
        snxt = __builtin_amdgcn_mfma_f32_32x32x16_bf16(kc[i], qf[i], snxt, 0, 0, 0);
    }
    // exp (log2 domain) + sum tree
#pragma unroll
    for (int r = 0; r < 16; ++r) p[r] = exp2v(p[r] - m_run);
    float sSum = ((p[0] + p[1]) + (p[2] + p[3])) + ((p[4] + p[5]) + (p[6] + p[7])) +
                 (((p[8] + p[9]) + (p[10] + p[11])) + ((p[12] + p[13]) + (p[14] + p[15])));
    sSum += __shfl_xor(sSum, 32);
    l_run += sSum;

    // P -> bf16 B-frags via cvt_pk + permlane32_swap
    unsigned x0 = cvtpk(p[0], p[1]), x1 = cvtpk(p[2], p[3]);
    unsigned y0 = cvtpk(p[4], p[5]), y1 = cvtpk(p[6], p[7]);
    PSWAP(x0, y0); PSWAP(x1, y1);
    uint4v u0 = {x0, x1, y0, y1};
    v8bf pf0 = __builtin_bit_cast(v8bf, u0);
    unsigned z0 = cvtpk(p[8], p[9]), z1 = cvtpk(p[10], p[11]);
    unsigned w0 = cvtpk(p[12], p[13]), w1 = cvtpk(p[14], p[15]);
    PSWAP(z0, w0); PSWAP(z1, w1);
    uint4v u1 = {z0, z1, w0, w1};
    v8bf pf1 = __builtin_bit_cast(v8bf, u1);

    // PV(t)
#pragma unroll
    for (int dd = 0; dd < 4; ++dd) {
      acc[dd] = __builtin_amdgcn_mfma_f32_32x32x16_bf16(vf0[dd], pf0, acc[dd], 0, 0, 0);
      acc[dd] = __builtin_amdgcn_mfma_f32_32x32x16_bf16(vf1[dd], pf1, acc[dd], 0, 0, 0);
    }

    if (nexttile) {
      // write S(t+1) to ring buffer
      int bw = (kt + 1) & 3;
#pragma unroll
      for (int r4 = 0; r4 < 4; ++r4) {
        f32x4 vv = {snxt[r4 * 4 + 0], snxt[r4 * 4 + 1], snxt[r4 * 4 + 2], snxt[r4 * 4 + 3]};
        *(f32x4*)&sx[bw][wv][r4][l][0] = vv;
      }
      // prefetch K(t+2)
      int kt2 = (kt + 2 < 50) ? kt + 2 : 0;
#pragma unroll
      for (int i = 0; i < 8; ++i)
        kc[i] = *(const v8bf*)(kbase + (size_t)i * 25600 + (kt2 * 32 + l31) * 16);
      // prefetch V(t+1)
      const unsigned short* vp = vbase + (size_t)(kt + 1) * 8192;
#pragma unroll
      for (int i = 0; i < 4; ++i) vf0[i] = *(const v8bf*)(vp + i * 256);
#pragma unroll
      for (int i = 0; i < 4; ++i) vf1[i] = *(const v8bf*)(vp + 4096 + i * 256);
    }
  };

  for (int kt = 0; kt < 48; kt += 2) {
    body(kt, sA, sB, true);
    body(kt + 1, sB, sA, true);
  }
  body(48, sA, sB, true);
  body(49, sB, sA, false);

  // epilogue: out = x + gamma * O / l   (own d-half; lanes = consecutive q)
  float inv = 1.f / l_run;
  float gm = gamma[0];
#pragma unroll
  for (int dd = 0; dd < 4; ++dd) {
#pragma unroll
    for (int r = 0; r < 16; ++r) {
      int d = (dto32 + dd) * 32 + (r & 3) + 8 * (r >> 2) + 4 * hi;
      size_t base = ((size_t)n * 256 + d) * HWP + q0 + l31;
      out[base] = x[base] + gm * acc[dd][r] * inv;
    }
  }
}

// ---------------- launcher ----------------
extern "C" void kernel_launch(void* const* d_in, const int* in_sizes, int n_in,
                              void* d_out, int out_size, void* d_ws, size_t ws_size,
                              hipStream_t stream) {
  const float* x     = (const float*)d_in[0];
  const float* ln_w  = (const float*)d_in[1];
  const float* ln_b  = (const float*)d_in[2];
  const float* qkv_w = (const float*)d_in[3];
  const float* qkv_b = (const float*)d_in[4];
  const float* gamma = (const float*)d_in[5];
  float* out = (float*)d_out;

  char* ws = (char*)d_ws;
  unsigned short* w_frag = (unsigned short*)ws;              //   393,216 B
  float*          pe     = (float*)(ws + 393216);            // 1,638,400 B
  unsigned short* q_arr  = (unsigned short*)(ws + 2031616);    // 13,107,200 B
  unsigned short* k_arr  = (unsigned short*)(ws + 15138816);   // 13,107,200 B
  unsigned short* v_arr  = (unsigned short*)(ws + 28246016);   // 13,107,200 B

  hipLaunchKernelGGL(prep_kernel, dim3(384), dim3(256), 0, stream, qkv_w, pe, w_frag);
  hipLaunchKernelGGL(ln_qkv_kernel, dim3(400), dim3(512), 0, stream,
                     x, ln_w, ln_b, w_frag, qkv_b, pe, q_arr, k_arr, v_arr);
  hipLaunchKernelGGL(attn_kernel, dim3(800), dim3(128), 0, stream,
                     q_arr, k_arr, v_arr, x, gamma, out);
}